// Round 7
// baseline (25132.503 us; speedup 1.0000x reference)
//
#include <hip/hip_runtime.h>
#include <cmath>

// LIF_complex round 7: round-5 proven skeleton + round-6's two good ideas,
// de-risked (round 6 shipped 4 untested mechanisms at once and hung):
//  - per-lane direct register polls of the PROVEN 8-byte {tag=t | g} slots:
//    16 waves = 2 row-groups x 8 col-groups; each lane needs exactly 4 g
//    values = 4 parallel u64 agent atomic loads. No LDS g staging, no
//    barrier A, no gs bank conflicts (round 5: 1.34e8 conflicts).
//  - w pinned in VGPRs via 32 NAMED SCALAR floats + in-loop asm "+v" uses.
//    The asm is opaque: its outputs cannot be recreated by reloading w from
//    memory, so the cross-iteration def-use chain forces register residency
//    (rounds 1/2/3/5: VGPR_Count 56/60/40/44 = every array/vector variant
//    got rematerialized from L2 every step).
//  - ONE __syncthreads per step. preduce is parity-double-buffered: a wave
//    whose polled columns belong to other blocks can run one step ahead of
//    its own wave 0 (its poll is gated by OTHER blocks' publishes), so
//    step t+1 preduce writes may precede wave-0's step-t reads.
//  - outputs in parity-double-buffered LDS windows, dumped by all threads
//    every 64 steps (dump reads old parity; wave-0 writes new parity).
// Protocol (proven r3/r5): parity double-buffered slots, tag = full t.
// Block publishes t only after all its waves observed all tags t-1, which
// transitively certifies every block finished reading the t-2 values being
// overwritten.

#define T_STEPS 8192
#define NN      2048
#define NBLK    128
#define NTHR    1024
#define RPB     16
#define DUMP    64

typedef unsigned long long u64;
typedef unsigned int       u32;

__device__ __forceinline__ float stable_sigmoid(float x) {
    if (x >= 0.0f) {
        return 1.0f / (1.0f + expf(-x));
    } else {
        float e = expf(x);
        return e / (1.0f + e);
    }
}

__device__ __forceinline__ u64 slot_ld(const u64* p) {
    return __hip_atomic_load(p, __ATOMIC_RELAXED, __HIP_MEMORY_SCOPE_AGENT);
}

__global__ __launch_bounds__(NTHR, 4) void lif_kernel(
    const float* __restrict__ x_in,    // [T, N]
    const float* __restrict__ w,       // [N, N]
    const float* __restrict__ v_rest,  // [N]
    const float* __restrict__ tau_m,   // [N]
    const float* __restrict__ tau_g,   // [N]
    const float* __restrict__ pre_cp,  // [1]
    const float* __restrict__ post_cp, // [1]
    const float* __restrict__ v0,      // [N]
    const float* __restrict__ g0,      // [N]
    float* __restrict__ out,           // [2, T, N]
    u64* __restrict__ slots)           // [2, N] tagged g slots (ws)
{
    __shared__ float preduce[2][8][RPB];   // [step parity][col group][row]
    __shared__ float vbuf[2][DUMP][RPB];   // [window parity][step][row]
    __shared__ float sbuf[2][DUMP][RPB];

    const int tid = threadIdx.x;
    const int b   = blockIdx.x;
    const int wv  = tid >> 6;
    const int i   = wv & 1;            // row group: rows 8i..8i+7
    const int j   = wv >> 1;           // col group: cols 256j..256j+255
    const int k   = tid & 63;          // lane
    const int colbase = 256 * j + 4 * k;   // this lane's 4 columns

    // ---- w: 8 rows x 4 cols per lane, 32 named scalars (16B/lane coalesced)
    const float* wb = w + (size_t)(b * RPB + 8 * i) * NN + colbase;
    float w00, w01, w02, w03, w10, w11, w12, w13;
    float w20, w21, w22, w23, w30, w31, w32, w33;
    float w40, w41, w42, w43, w50, w51, w52, w53;
    float w60, w61, w62, w63, w70, w71, w72, w73;
    {
        float4 t4;
        t4 = *(const float4*)(wb);          w00=t4.x; w01=t4.y; w02=t4.z; w03=t4.w;
        t4 = *(const float4*)(wb + NN);     w10=t4.x; w11=t4.y; w12=t4.z; w13=t4.w;
        t4 = *(const float4*)(wb + 2*NN);   w20=t4.x; w21=t4.y; w22=t4.z; w23=t4.w;
        t4 = *(const float4*)(wb + 3*NN);   w30=t4.x; w31=t4.y; w32=t4.z; w33=t4.w;
        t4 = *(const float4*)(wb + 4*NN);   w40=t4.x; w41=t4.y; w42=t4.z; w43=t4.w;
        t4 = *(const float4*)(wb + 5*NN);   w50=t4.x; w51=t4.y; w52=t4.z; w53=t4.w;
        t4 = *(const float4*)(wb + 6*NN);   w60=t4.x; w61=t4.y; w62=t4.z; w63=t4.w;
        t4 = *(const float4*)(wb + 7*NN);   w70=t4.x; w71=t4.y; w72=t4.z; w73=t4.w;
    }

    const float pre_c  = pre_cp[0];
    const float post_c = post_cp[0];

    // ---- neuron state: wave 0, lanes 0..15
    float vr = 0.f, tm = 1.f, tg = 1.f, v = 0.f, g = 0.f;
    if (wv == 0 && k < RPB) {
        const int n = b * RPB + k;
        vr = v_rest[n]; tm = tau_m[n]; tg = tau_g[n];
        v  = v0[n];     g  = g0[n];
    }

    for (int t = 0; t < T_STEPS; ++t) {
        // opaque in-loop uses: w scalars cannot be rematerialized across this
        asm volatile("" : "+v"(w00), "+v"(w01), "+v"(w02), "+v"(w03),
                          "+v"(w10), "+v"(w11), "+v"(w12), "+v"(w13));
        asm volatile("" : "+v"(w20), "+v"(w21), "+v"(w22), "+v"(w23),
                          "+v"(w30), "+v"(w31), "+v"(w32), "+v"(w33));
        asm volatile("" : "+v"(w40), "+v"(w41), "+v"(w42), "+v"(w43),
                          "+v"(w50), "+v"(w51), "+v"(w52), "+v"(w53));
        asm volatile("" : "+v"(w60), "+v"(w61), "+v"(w62), "+v"(w63),
                          "+v"(w70), "+v"(w71), "+v"(w72), "+v"(w73));

        float x = 0.0f;
        if (wv == 0 && k < RPB)
            x = x_in[(size_t)t * NN + b * RPB + k];   // issued before polls

        // ---- acquire this lane's 4 g values (4 parallel tagged polls)
        float gA, gB, gC, gD;
        if (t == 0) {
            float4 g4 = *(const float4*)(g0 + colbase);
            gA = g4.x; gB = g4.y; gC = g4.z; gD = g4.w;
        } else {
            const unsigned want = (unsigned)(t - 1);
            const u64* sl = slots + (size_t)((t - 1) & 1) * NN + colbase;
            u64 e0 = slot_ld(sl + 0), e1 = slot_ld(sl + 1);
            u64 e2 = slot_ld(sl + 2), e3 = slot_ld(sl + 3);
            while ((u32)(e0 >> 32) != want || (u32)(e1 >> 32) != want ||
                   (u32)(e2 >> 32) != want || (u32)(e3 >> 32) != want) {
                __builtin_amdgcn_s_sleep(1);
                e0 = slot_ld(sl + 0); e1 = slot_ld(sl + 1);
                e2 = slot_ld(sl + 2); e3 = slot_ld(sl + 3);
            }
            gA = __uint_as_float((u32)e0); gB = __uint_as_float((u32)e1);
            gC = __uint_as_float((u32)e2); gD = __uint_as_float((u32)e3);
        }

        // ---- dot: 8 rows x 4 cols from registers
        float a0 = fmaf(w00, gA, fmaf(w01, gB, fmaf(w02, gC, w03 * gD)));
        float a1 = fmaf(w10, gA, fmaf(w11, gB, fmaf(w12, gC, w13 * gD)));
        float a2 = fmaf(w20, gA, fmaf(w21, gB, fmaf(w22, gC, w23 * gD)));
        float a3 = fmaf(w30, gA, fmaf(w31, gB, fmaf(w32, gC, w33 * gD)));
        float a4 = fmaf(w40, gA, fmaf(w41, gB, fmaf(w42, gC, w43 * gD)));
        float a5 = fmaf(w50, gA, fmaf(w51, gB, fmaf(w52, gC, w53 * gD)));
        float a6 = fmaf(w60, gA, fmaf(w61, gB, fmaf(w62, gC, w63 * gD)));
        float a7 = fmaf(w70, gA, fmaf(w71, gB, fmaf(w72, gC, w73 * gD)));

        // ---- distributed reduce: after this, lane l holds the full wave
        // sum for row 8i + (l&7)
        float snd, rcv;
        // mask 1: 8 accs -> 4 (keep row-bit0 == lane-bit0)
        snd = (k & 1) ? a0 : a1; rcv = __shfl_xor(snd, 1, 64);
        a0 = ((k & 1) ? a1 : a0) + rcv;
        snd = (k & 1) ? a2 : a3; rcv = __shfl_xor(snd, 1, 64);
        a1 = ((k & 1) ? a3 : a2) + rcv;
        snd = (k & 1) ? a4 : a5; rcv = __shfl_xor(snd, 1, 64);
        a2 = ((k & 1) ? a5 : a4) + rcv;
        snd = (k & 1) ? a6 : a7; rcv = __shfl_xor(snd, 1, 64);
        a3 = ((k & 1) ? a7 : a6) + rcv;
        // mask 2: 4 -> 2
        snd = (k & 2) ? a0 : a1; rcv = __shfl_xor(snd, 2, 64);
        a0 = ((k & 2) ? a1 : a0) + rcv;
        snd = (k & 2) ? a2 : a3; rcv = __shfl_xor(snd, 2, 64);
        a1 = ((k & 2) ? a3 : a2) + rcv;
        // mask 4: 2 -> 1
        snd = (k & 4) ? a0 : a1; rcv = __shfl_xor(snd, 4, 64);
        a0 = ((k & 4) ? a1 : a0) + rcv;
        // masks 8,16,32: plain butterfly across the eight 8-lane groups
        a0 += __shfl_xor(a0, 8, 64);
        a0 += __shfl_xor(a0, 16, 64);
        a0 += __shfl_xor(a0, 32, 64);

        const int par = t & 1;
        if (k < 8) preduce[par][j][8 * i + k] = a0;
        __syncthreads();   // the step's single barrier

        // ---- neuron update + publish (wave 0, lanes 0..15)
        if (wv == 0 && k < RPB) {
            float u = ((preduce[par][0][k] + preduce[par][1][k])
                     + (preduce[par][2][k] + preduce[par][3][k]))
                    + ((preduce[par][4][k] + preduce[par][5][k])
                     + (preduce[par][6][k] + preduce[par][7][k]));
            float I = post_c * stable_sigmoid(pre_c * (u + x));
            g = g - g / tg;
            v = v + (vr - v + I) / tm;
            float soft = stable_sigmoid(v - 30.0f);
            bool  spk  = (v >= 30.0f);
            v = spk ? vr : v;
            g = spk ? 1.0f : g;
            u64 pk = ((u64)(u32)t << 32) | (u64)__float_as_uint(g);
            __hip_atomic_store(slots + (size_t)par * NN + b * RPB + k, pk,
                               __ATOMIC_RELAXED, __HIP_MEMORY_SCOPE_AGENT);
            const int wpar = (t >> 6) & 1;
            vbuf[wpar][t & (DUMP - 1)][k] = v;
            sbuf[wpar][t & (DUMP - 1)][k] = soft;
        }

        // ---- window dump (all threads, old parity; 2 stores/thread)
        if ((t & (DUMP - 1)) == 0 && t != 0) {
            const int t0   = t - DUMP;
            const int rpar = ((t >> 6) & 1) ^ 1;
            const int s    = tid >> 4;
            const int rr   = tid & 15;
            size_t o = (size_t)(t0 + s) * NN + b * RPB + rr;
            out[o] = vbuf[rpar][s][rr];
            out[(size_t)T_STEPS * NN + o] = sbuf[rpar][s][rr];
        }
    }

    // ---- final window [T-64, T-1]
    __syncthreads();
    {
        const int t0   = T_STEPS - DUMP;
        const int rpar = ((T_STEPS - 1) >> 6) & 1;
        const int s    = tid >> 4;
        const int rr   = tid & 15;
        size_t o = (size_t)(t0 + s) * NN + b * RPB + rr;
        out[o] = vbuf[rpar][s][rr];
        out[(size_t)T_STEPS * NN + o] = sbuf[rpar][s][rr];
    }
}

extern "C" void kernel_launch(void* const* d_in, const int* in_sizes, int n_in,
                              void* d_out, int out_size, void* d_ws, size_t ws_size,
                              hipStream_t stream) {
    const float* x_in   = (const float*)d_in[0];
    const float* w      = (const float*)d_in[1];
    const float* v_rest = (const float*)d_in[2];
    const float* tau_m  = (const float*)d_in[3];
    const float* tau_g  = (const float*)d_in[4];
    const float* pre_c  = (const float*)d_in[5];
    const float* post_c = (const float*)d_in[6];
    const float* v0     = (const float*)d_in[7];
    const float* g0     = (const float*)d_in[8];
    float* out = (float*)d_out;

    u64* slots = (u64*)d_ws;  // [2, NN] 8-byte tagged slots

    // tag 0xFFFFFFFF never matches any t in [0, 8192)
    hipMemsetAsync(slots, 0xFF, 2 * NN * sizeof(u64), stream);

    void* args[] = {
        (void*)&x_in, (void*)&w, (void*)&v_rest, (void*)&tau_m, (void*)&tau_g,
        (void*)&pre_c, (void*)&post_c, (void*)&v0, (void*)&g0,
        (void*)&out, (void*)&slots
    };
    hipLaunchCooperativeKernel((void*)lif_kernel, dim3(NBLK), dim3(NTHR),
                               args, 0, stream);
}